// Round 4
// baseline (144.471 us; speedup 1.0000x reference)
//
#include <hip/hip_runtime.h>
#include <math.h>

#define NS 512
#define ND 256
#define LIST_CAP 32768u

typedef short short8 __attribute__((ext_vector_type(8)));
typedef float f32x16 __attribute__((ext_vector_type(16)));

__device__ __forceinline__ unsigned short bf16_rne(float x) {
  unsigned u = __float_as_uint(x);
  unsigned r = u + 0x7fffu + ((u >> 16) & 1u);
  return (unsigned short)(r >> 16);
}
__device__ __forceinline__ float bf16_tof(unsigned short h) {
  return __uint_as_float(((unsigned)h) << 16);
}
__device__ __forceinline__ void bsplit(float x, unsigned short& h, unsigned short& l) {
  h = bf16_rne(x);
  l = bf16_rne(x - bf16_tof(h));
}
__device__ __forceinline__ float wave_sum(float v) {
  v += __shfl_xor(v, 1);  v += __shfl_xor(v, 2);  v += __shfl_xor(v, 4);
  v += __shfl_xor(v, 8);  v += __shfl_xor(v, 16); v += __shfl_xor(v, 32);
  return v;
}

// 4 operand fragments for one kc step: A hi, A lo, B hi, B lo (32 rows each side)
#define GLOADS4(S, kc) do { \
  S[0] = *(const short8*)(pAh + (kc)); \
  S[1] = *(const short8*)(pAl + (kc)); \
  S[2] = *(const short8*)(pBh + (kc)); \
  S[3] = *(const short8*)(pBl + (kc)); \
} while (0)

// split-bf16: hi*hi + hi*lo + lo*hi into one fp32 accumulator
#define GMFMA3(S) do { \
  acc = __builtin_amdgcn_mfma_f32_32x32x16_bf16(S[0], S[2], acc, 0, 0, 0); \
  acc = __builtin_amdgcn_mfma_f32_32x32x16_bf16(S[0], S[3], acc, 0, 0, 0); \
  acc = __builtin_amdgcn_mfma_f32_32x32x16_bf16(S[1], S[2], acc, 0, 0, 0); \
} while (0)

// K1: norms + normalized bf16 split of context; fused weight transpose+split;
// zero sparse counter. Blocks 0..4095: ctx rows; 4096..4607: W cols.
__global__ __launch_bounds__(256)
void k_prep(const float* __restrict__ ctx, const float* __restrict__ Wg,
            const float* __restrict__ Wa,
            float* __restrict__ nrm, float* __restrict__ nsq,
            unsigned short* __restrict__ cnhi, unsigned short* __restrict__ cnlo,
            unsigned short* __restrict__ wgthi, unsigned short* __restrict__ wgtlo,
            unsigned short* __restrict__ wathi, unsigned short* __restrict__ watlo,
            unsigned* __restrict__ cnt)
{
  if (blockIdx.x >= 4096) {
    int wb = blockIdx.x - 4096;
    int j = wb & 255, selA = wb >> 8;
    int k = threadIdx.x;
    if (wb == 0 && k == 0) *cnt = 0u;
    const float* W = selA ? Wa : Wg;
    unsigned short h, l;
    bsplit(W[k * ND + j], h, l);
    if (selA) { wathi[j * ND + k] = h; watlo[j * ND + k] = l; }
    else      { wgthi[j * ND + k] = h; wgtlo[j * ND + k] = l; }
    return;
  }
  int w = threadIdx.x >> 6, lane = threadIdx.x & 63;
  int g = blockIdx.x * 4 + w;
  float4 v = ((const float4*)ctx)[(size_t)g * 64 + lane];
  float ss = v.x*v.x + v.y*v.y + v.z*v.z + v.w*v.w;
  ss = wave_sum(ss);
  float n = sqrtf(ss);
  float rn = 1.f / fmaxf(n, 1e-12f);
  if (lane == 0) { nrm[g] = n; nsq[g] = ss; }
  ushort4 hi, lo;
  bsplit(v.x * rn, hi.x, lo.x);
  bsplit(v.y * rn, hi.y, lo.y);
  bsplit(v.z * rn, hi.z, lo.z);
  bsplit(v.w * rn, hi.w, lo.w);
  ((ushort4*)cnhi)[(size_t)g * 64 + lane] = hi;
  ((ushort4*)cnlo)[(size_t)g * 64 + lane] = lo;
}

// K2: gram via split-bf16 MFMA. 64x64 tile per block over the 8x8 symmetric
// tile grid (36 pairs x 32 batches = 1152 blocks, 4.5 waves/SIMD). Each wave
// computes one 32x32 quadrant. Register-pipelined K loop (depth 3).
__global__ __launch_bounds__(256, 4)
void k_gram2(const unsigned short* __restrict__ cnhi, const unsigned short* __restrict__ cnlo,
             const float* __restrict__ nrm,
             float* __restrict__ rowp, float* __restrict__ diag,
             float* __restrict__ pA2, float* __restrict__ pA3,
             unsigned* __restrict__ cnt, unsigned* __restrict__ keys,
             float* __restrict__ vals)
{
  __shared__ float s_row[2][64];
  __shared__ float s_col[2][64];
  __shared__ float sred[8];
  const int bx0 = blockIdx.x;
  const int bx = (bx0 & 7) * 144 + (bx0 >> 3);   // XCD swizzle (1152 = 8*144)
  const int b = bx / 36;
  int rem = bx % 36, ti = 0;
  #pragma unroll
  for (int q = 0; q < 7; ++q) { if (rem >= 8 - ti) { rem -= 8 - ti; ++ti; } }
  const int tj = ti + rem;
  const bool diagT = (ti == tj);
  const int i0 = ti * 64, j0 = tj * 64;
  const int bB = b * NS;
  const int rbA = bB + i0, rbB = bB + j0;

  const int tid = threadIdx.x;
  const int lane = tid & 63, wid = tid >> 6;
  const int l31 = lane & 31, hl = lane >> 5;
  const int wr = wid >> 1, wc = wid & 1;

  const size_t offA = (size_t)(rbA + wr * 32 + l31) * ND + hl * 8;
  const size_t offB = (size_t)(rbB + wc * 32 + l31) * ND + hl * 8;
  const unsigned short* pAh = cnhi + offA;
  const unsigned short* pAl = cnlo + offA;
  const unsigned short* pBh = cnhi + offB;
  const unsigned short* pBl = cnlo + offB;

  f32x16 acc = {};
  short8 st[3][4];
  GLOADS4(st[0], 0);
  GLOADS4(st[1], 16);
  #pragma unroll
  for (int it = 0; it < 16; ++it) {
    const int cur = it % 3;
    const int nxt = (it + 2) % 3;
    if (it < 14) GLOADS4(st[nxt], (it + 2) * 16);
    GMFMA3(st[cur]);
  }

  // ---- epilogue ----
  const float nc = nrm[rbB + wc * 32 + l31];
  const int gcol = wc * 32 + l31;                 // local col 0..63
  float a2 = 0.f, a3 = 0.f, colsum = 0.f;

  #pragma unroll
  for (int r = 0; r < 16; ++r) {
    const int rofs = (r & 3) + 8 * (r >> 2) + 4 * hl;
    const int grow = wr * 32 + rofs;              // local row 0..63
    const float nr = nrm[rbA + grow];
    float v = acc[r];
    float adj = (v > 0.3f) ? v : 0.f;
    float q2 = adj * adj;
    a3 += q2;
    a2 += q2 * nr * nc;
    colsum += adj;
    if (diagT) {
      if (grow == gcol) {
        diag[bB + i0 + grow] = adj;
      } else if (adj > 0.f) {
        unsigned idx = atomicAdd(cnt, 1u);
        if (idx < LIST_CAP) {
          keys[idx] = (unsigned)((bB + i0 + grow) * NS + (j0 + gcol));
          vals[idx] = adj;
        }
      }
    } else if (adj > 0.f) {
      unsigned idx = atomicAdd(cnt, 2u);
      if (idx < LIST_CAP) {
        keys[idx] = (unsigned)((bB + i0 + grow) * NS + (j0 + gcol));
        vals[idx] = adj;
      }
      if (idx + 1u < LIST_CAP) {
        keys[idx + 1u] = (unsigned)((bB + j0 + gcol) * NS + (i0 + grow));
        vals[idx + 1u] = adj;
      }
    }
    float rs = adj;
    rs += __shfl_xor(rs, 1); rs += __shfl_xor(rs, 2); rs += __shfl_xor(rs, 4);
    rs += __shfl_xor(rs, 8); rs += __shfl_xor(rs, 16);
    if (l31 == 0) s_row[wc][grow] = rs;
  }
  colsum += __shfl_xor(colsum, 32);               // add the two hl halves
  if (!diagT && hl == 0) s_col[wr][gcol] = colsum;
  a2 = wave_sum(a2);
  a3 = wave_sum(a3);
  if (lane == 0) { sred[wid] = a2; sred[4 + wid] = a3; }
  __syncthreads();
  if (tid < 64) {
    rowp[tj * 16384 + rbA + tid] = s_row[0][tid] + s_row[1][tid];
    if (!diagT)
      rowp[ti * 16384 + rbB + tid] = s_col[0][tid] + s_col[1][tid];
  }
  if (tid == 0) {
    float f = diagT ? 1.f : 2.f;
    pA2[bx] = f * (sred[0] + sred[1] + sred[2] + sred[3]);
    pA3[bx] = f * (sred[4] + sred[5] + sred[6] + sred[7]);
  }
}

// K3: fused row combine (8 partial slices) + M build + sparse fixup + A1.
__global__ __launch_bounds__(256)
void k_mrow(const float* __restrict__ ctx, const float* __restrict__ rowp,
            const float* __restrict__ nsq, const float* __restrict__ diag,
            const unsigned* __restrict__ cnt, const unsigned* __restrict__ keys,
            const float* __restrict__ vals,
            unsigned short* __restrict__ Mhi, unsigned short* __restrict__ Mlo,
            float* __restrict__ pA1)
{
  __shared__ float sa[4];
  int tid = threadIdx.x, w = tid >> 6, lane = tid & 63;
  int g = blockIdx.x * 4 + w;
  float r = 0.f;
  #pragma unroll
  for (int s = 0; s < 8; ++s) r += rowp[s * 16384 + g];
  float rr = 1.f / (r + 1e-12f);
  float4 v = ((const float4*)ctx)[(size_t)g * 64 + lane];
  float s = diag[g] * rr;
  float mx = v.x * s, my = v.y * s, mz = v.z * s, mw = v.w * s;
  unsigned c = *cnt; if (c > LIST_CAP) c = LIST_CAP;
  for (unsigned e = 0; e < c; ++e) {
    unsigned key = keys[e];
    if ((key >> 9) == (unsigned)g) {
      float vv = vals[e] * rr;
      unsigned bm = ((unsigned)g & ~511u) | (key & 511u);
      float4 cv = ((const float4*)ctx)[(size_t)bm * 64 + lane];
      mx = fmaf(vv, cv.x, mx); my = fmaf(vv, cv.y, my);
      mz = fmaf(vv, cv.z, mz); mw = fmaf(vv, cv.w, mw);
    }
  }
  ushort4 hi, lo;
  bsplit(mx, hi.x, lo.x); bsplit(my, hi.y, lo.y);
  bsplit(mz, hi.z, lo.z); bsplit(mw, hi.w, lo.w);
  ((ushort4*)Mhi)[(size_t)g * 64 + lane] = hi;
  ((ushort4*)Mlo)[(size_t)g * 64 + lane] = lo;
  if (lane == 0) sa[w] = r * nsq[g];
  __syncthreads();
  if (tid == 0) pA1[blockIdx.x] = sa[0] + sa[1] + sa[2] + sa[3];
}

// K4: C = act(A @ W + bias), 64x64 tile per block (grid 256x4 = 1024 blocks),
// one 32x32 quadrant per wave, register-pipelined.
// MODE 0: relu, write bf16 hi/lo only. MODE 1: write fp32 only.
template<int MODE>
__global__ __launch_bounds__(256, 4)
void k_mm(const unsigned short* __restrict__ Ahi, const unsigned short* __restrict__ Alo,
          const unsigned short* __restrict__ Bthi, const unsigned short* __restrict__ Btlo,
          const float* __restrict__ bias, float* __restrict__ outf,
          unsigned short* __restrict__ Ohi, unsigned short* __restrict__ Olo)
{
  const int i0 = blockIdx.x * 64;
  const int c0 = blockIdx.y * 64;
  const int tid = threadIdx.x;
  const int lane = tid & 63, wid = tid >> 6;
  const int l31 = lane & 31, hl = lane >> 5;
  const int wr = wid >> 1, wc = wid & 1;

  const size_t offA = (size_t)(i0 + wr * 32 + l31) * ND + hl * 8;
  const size_t offB = (size_t)(c0 + wc * 32 + l31) * ND + hl * 8;
  const unsigned short* pAh = Ahi + offA;
  const unsigned short* pAl = Alo + offA;
  const unsigned short* pBh = Bthi + offB;
  const unsigned short* pBl = Btlo + offB;

  f32x16 acc = {};
  short8 st[3][4];
  GLOADS4(st[0], 0);
  GLOADS4(st[1], 16);
  #pragma unroll
  for (int it = 0; it < 16; ++it) {
    const int cur = it % 3;
    const int nxt = (it + 2) % 3;
    if (it < 14) GLOADS4(st[nxt], (it + 2) * 16);
    GMFMA3(st[cur]);
  }

  const int gcol = c0 + wc * 32 + l31;
  const float bv = bias[gcol];
  #pragma unroll
  for (int r = 0; r < 16; ++r) {
    const int rofs = (r & 3) + 8 * (r >> 2) + 4 * hl;
    const size_t grow = (size_t)(i0 + wr * 32 + rofs);
    float v = acc[r] + bv;
    if (MODE == 0) {
      v = fmaxf(v, 0.f);
      unsigned short h, l;
      bsplit(v, h, l);
      Ohi[grow * ND + gcol] = h;
      Olo[grow * ND + gcol] = l;
    } else {
      outf[grow * ND + gcol] = v;
    }
  }
}

// K5: per-row LayerNorm -> exact GELU -> dot with W_att2 -> wl
__global__ __launch_bounds__(256)
void k_ln(const float* __restrict__ a, const float* __restrict__ g,
          const float* __restrict__ bt, const float* __restrict__ W2,
          const float* __restrict__ b2, float* __restrict__ wl)
{
  int w = threadIdx.x >> 6, lane = threadIdx.x & 63;
  int row = blockIdx.x * 4 + w;
  float4 x = ((const float4*)a)[(size_t)row * 64 + lane];
  float s = x.x + x.y + x.z + x.w;
  float ss = fmaf(x.x, x.x, fmaf(x.y, x.y, fmaf(x.z, x.z, x.w * x.w)));
  s = wave_sum(s); ss = wave_sum(ss);
  float mu = s * (1.f / 256.f);
  float var = ss * (1.f / 256.f) - mu * mu;
  float rstd = rsqrtf(fmaxf(var, 0.f) + 1e-5f);
  float4 gg = ((const float4*)g)[lane];
  float4 bb = ((const float4*)bt)[lane];
  float4 wv = ((const float4*)W2)[lane];
  const float inv_sqrt2 = 0.70710678118654752f;
  float d = 0.f;
  float y = (x.x - mu) * rstd * gg.x + bb.x;
  d = fmaf(0.5f * y * (1.f + erff(y * inv_sqrt2)), wv.x, d);
  y = (x.y - mu) * rstd * gg.y + bb.y;
  d = fmaf(0.5f * y * (1.f + erff(y * inv_sqrt2)), wv.y, d);
  y = (x.z - mu) * rstd * gg.z + bb.z;
  d = fmaf(0.5f * y * (1.f + erff(y * inv_sqrt2)), wv.z, d);
  y = (x.w - mu) * rstd * gg.w + bb.w;
  d = fmaf(0.5f * y * (1.f + erff(y * inv_sqrt2)), wv.w, d);
  d = wave_sum(d);
  if (lane == 0) wl[row] = d + b2[0];
}

// K6: per-(batch, 64-row chunk) masked softmax (recomputed per block) +
// partial weighted pool of h (reconstructed from bf16 hi/lo). 256 blocks.
__global__ __launch_bounds__(256)
void k_pool2(const float* __restrict__ wl, const int* __restrict__ amask,
             const unsigned short* __restrict__ hhi, const unsigned short* __restrict__ hlo,
             float* __restrict__ part)
{
  __shared__ float sw[512];
  __shared__ float red[256];
  int b = blockIdx.x >> 3, p = blockIdx.x & 7, t = threadIdx.x;
  float l0 = (amask[b * NS + t]       == 0) ? -INFINITY : wl[b * NS + t];
  float l1 = (amask[b * NS + 256 + t] == 0) ? -INFINITY : wl[b * NS + 256 + t];
  red[t] = fmaxf(l0, l1);
  __syncthreads();
  for (int s = 128; s; s >>= 1) { if (t < s) red[t] = fmaxf(red[t], red[t + s]); __syncthreads(); }
  float mx = red[0];
  __syncthreads();
  float e0 = expf(l0 - mx), e1 = expf(l1 - mx);
  red[t] = e0 + e1;
  __syncthreads();
  for (int s = 128; s; s >>= 1) { if (t < s) red[t] += red[t + s]; __syncthreads(); }
  float inv = 1.f / red[0];
  sw[t] = e0 * inv; sw[256 + t] = e1 * inv;
  __syncthreads();
  const size_t base = (size_t)b * NS * ND + (size_t)p * 64 * ND + t;
  float acc = 0.f;
  #pragma unroll 8
  for (int n = 0; n < 64; ++n) {
    float hv = bf16_tof(hhi[base + (size_t)n * ND]) + bf16_tof(hlo[base + (size_t)n * ND]);
    acc = fmaf(sw[p * 64 + n], hv, acc);
  }
  part[(size_t)blockIdx.x * ND + t] = acc;
}

// K7: blocks 0..31: combine pooled partials + logits. Block 32: graph loss.
__global__ __launch_bounds__(256)
void k_final(const float* __restrict__ part, const float* __restrict__ W_out,
             const float* __restrict__ b_out, const float* __restrict__ pA1,
             const float* __restrict__ pA2, const float* __restrict__ pA3,
             float* __restrict__ out)
{
  __shared__ float red[512];
  int t = threadIdx.x;
  if (blockIdx.x < 32) {
    int b = blockIdx.x;
    float pl = 0.f;
    #pragma unroll
    for (int p = 0; p < 8; ++p) pl += part[(size_t)(b * 8 + p) * ND + t];
    red[t]       = pl * W_out[t * 2 + 0];
    red[256 + t] = pl * W_out[t * 2 + 1];
    __syncthreads();
    for (int s = 128; s; s >>= 1) {
      if (t < s) { red[t] += red[t + s]; red[256 + t] += red[256 + t + s]; }
      __syncthreads();
    }
    if (t == 0) {
      out[b * 2 + 0] = red[0]   + b_out[0];
      out[b * 2 + 1] = red[256] + b_out[1];
    }
  } else {
    float r1 = 0.f;
    #pragma unroll
    for (int i = 0; i < 16; ++i) r1 += pA1[i * 256 + t];
    float r2 = 0.f, r3 = 0.f;
    #pragma unroll
    for (int i = 0; i < 5; ++i) {
      int idx = i * 256 + t;
      if (idx < 1152) { r2 += pA2[idx]; r3 += pA3[idx]; }
    }
    red[t] = r1; red[256 + t] = r2;
    __syncthreads();
    for (int s = 128; s; s >>= 1) {
      if (t < s) { red[t] += red[t + s]; red[256 + t] += red[256 + t + s]; }
      __syncthreads();
    }
    r1 = red[0]; r2 = red[256];
    __syncthreads();
    red[t] = r3;
    __syncthreads();
    for (int s = 128; s; s >>= 1) { if (t < s) red[t] += red[t + s]; __syncthreads(); }
    if (t == 0) {
      float smooth = 0.2f * (r1 - r2) * (1.f / (32.f * 512.f * 512.f));
      float spars  = 0.1f * red[0] * (1.f / (512.f * 512.f)) * (1.f / 32.f);
      out[64] = smooth + spars;
    }
  }
}

extern "C" void kernel_launch(void* const* d_in, const int* in_sizes, int n_in,
                              void* d_out, int out_size, void* d_ws, size_t ws_size,
                              hipStream_t stream)
{
  (void)in_sizes; (void)n_in; (void)out_size; (void)ws_size;
  const float* ctx    = (const float*)d_in[0];
  const int*   amask  = (const int*)d_in[1];
  const float* W_gcn  = (const float*)d_in[2];
  const float* b_gcn  = (const float*)d_in[3];
  const float* W_att1 = (const float*)d_in[4];
  const float* b_att1 = (const float*)d_in[5];
  const float* ln_g   = (const float*)d_in[6];
  const float* ln_b   = (const float*)d_in[7];
  const float* W_att2 = (const float*)d_in[8];
  const float* b_att2 = (const float*)d_in[9];
  const float* W_out  = (const float*)d_in[10];
  const float* b_out  = (const float*)d_in[11];
  float* out = (float*)d_out;

  float* ws = (float*)d_ws;
  // W0 (16.8 MB): cn hi/lo, later reused as h hi/lo
  unsigned short* cnhi = (unsigned short*)ws;
  unsigned short* cnlo = (unsigned short*)(ws + 2097152);
  unsigned short* hhi  = cnhi;
  unsigned short* hlo  = cnlo;
  // W1 (16.8 MB): spare (unused this round)
  // W2 (16.8 MB): M hi/lo, later reused as 'a' fp32
  unsigned short* Mhi = (unsigned short*)(ws + 8388608);
  unsigned short* Mlo = (unsigned short*)(ws + 8388608 + 2097152);
  float* abuf = ws + 8388608;
  // small region
  float* sp   = ws + 12582912;
  float* nrm  = sp;            sp += 16384;
  float* nsq  = sp;            sp += 16384;
  float* rowp = sp;            sp += 131072;   // 8 partial slices
  float* diag = sp;            sp += 16384;
  float* wl   = sp;            sp += 16384;
  float* pA1  = sp;            sp += 4096;
  float* pA2  = sp;            sp += 1280;
  float* pA3  = sp;            sp += 1280;
  float* part = sp;            sp += 65536;
  unsigned* cnt  = (unsigned*)sp;  sp += 64;
  unsigned* keys = (unsigned*)sp;  sp += 32768;
  float* vals = sp;            sp += 32768;
  unsigned short* wgthi = (unsigned short*)sp; sp += 32768;
  unsigned short* wgtlo = (unsigned short*)sp; sp += 32768;
  unsigned short* wathi = (unsigned short*)sp; sp += 32768;
  unsigned short* watlo = (unsigned short*)sp; sp += 32768;

  k_prep<<<4608, 256, 0, stream>>>(ctx, W_gcn, W_att1, nrm, nsq, cnhi, cnlo,
                                   wgthi, wgtlo, wathi, watlo, cnt);
  k_gram2<<<1152, 256, 0, stream>>>(cnhi, cnlo, nrm, rowp, diag, pA2, pA3,
                                    cnt, keys, vals);
  k_mrow<<<4096, 256, 0, stream>>>(ctx, rowp, nsq, diag, cnt, keys, vals,
                                   Mhi, Mlo, pA1);
  k_mm<0><<<dim3(256, 4), 256, 0, stream>>>(Mhi, Mlo, wgthi, wgtlo, b_gcn,
                                            nullptr, hhi, hlo);
  k_mm<1><<<dim3(256, 4), 256, 0, stream>>>(hhi, hlo, wathi, watlo, b_att1,
                                            abuf, nullptr, nullptr);
  k_ln<<<4096, 256, 0, stream>>>(abuf, ln_g, ln_b, W_att2, b_att2, wl);
  k_pool2<<<256, 256, 0, stream>>>(wl, amask, hhi, hlo, part);
  k_final<<<33, 256, 0, stream>>>(part, W_out, b_out, pA1, pA2, pA3, out);
}

// Round 5
// 143.747 us; speedup vs baseline: 1.0050x; 1.0050x over previous
//
#include <hip/hip_runtime.h>
#include <math.h>

#define NS 512
#define ND 256
#define LIST_CAP 32768u

typedef short short8 __attribute__((ext_vector_type(8)));
typedef float f32x16 __attribute__((ext_vector_type(16)));

__device__ __forceinline__ unsigned short bf16_rne(float x) {
  unsigned u = __float_as_uint(x);
  unsigned r = u + 0x7fffu + ((u >> 16) & 1u);
  return (unsigned short)(r >> 16);
}
__device__ __forceinline__ float bf16_tof(unsigned short h) {
  return __uint_as_float(((unsigned)h) << 16);
}
__device__ __forceinline__ void bsplit(float x, unsigned short& h, unsigned short& l) {
  h = bf16_rne(x);
  l = bf16_rne(x - bf16_tof(h));
}
__device__ __forceinline__ float wave_sum(float v) {
  v += __shfl_xor(v, 1);  v += __shfl_xor(v, 2);  v += __shfl_xor(v, 4);
  v += __shfl_xor(v, 8);  v += __shfl_xor(v, 16); v += __shfl_xor(v, 32);
  return v;
}

// ---- K-loop building blocks -------------------------------------------------
// One k-step fragment set: A hi, A lo, B hi, B lo (short8 = 16B each).
#define GLOADS4(S, kc) do { \
  S[0] = *(const short8*)(pAh + (kc)); \
  S[1] = *(const short8*)(pAl + (kc)); \
  S[2] = *(const short8*)(pBh + (kc)); \
  S[3] = *(const short8*)(pBl + (kc)); \
} while (0)

// split-bf16: hi*hi + hi*lo + lo*hi into one fp32 accumulator
#define GMFMA3(S) do { \
  acc = __builtin_amdgcn_mfma_f32_32x32x16_bf16(S[0], S[2], acc, 0, 0, 0); \
  acc = __builtin_amdgcn_mfma_f32_32x32x16_bf16(S[0], S[3], acc, 0, 0, 0); \
  acc = __builtin_amdgcn_mfma_f32_32x32x16_bf16(S[1], S[2], acc, 0, 0, 0); \
} while (0)

// Batch of 4 k-steps (explicit compile-time indices; rule-20 safe)
#define LOADB(S, kc0) do { \
  GLOADS4(S[0], (kc0)); GLOADS4(S[1], (kc0) + 16); \
  GLOADS4(S[2], (kc0) + 32); GLOADS4(S[3], (kc0) + 48); \
} while (0)
#define MFMAB(S) do { \
  GMFMA3(S[0]); GMFMA3(S[1]); GMFMA3(S[2]); GMFMA3(S[3]); \
} while (0)
#define SB __builtin_amdgcn_sched_barrier(0)

// Full K=256 pipelined main loop: 4 batches, 2 live buffers, fenced phases.
#define KLOOP_PIPE do { \
  LOADB(s0, 0); \
  LOADB(s1, 64); \
  SB; MFMAB(s0); SB; \
  LOADB(s0, 128); \
  SB; MFMAB(s1); SB; \
  LOADB(s1, 192); \
  SB; MFMAB(s0); SB; \
  MFMAB(s1); \
} while (0)

// K1: norms + normalized bf16 split of context; fused weight transpose+split;
// zero sparse counter. Blocks 0..4095: ctx rows; 4096..4607: W cols.
__global__ __launch_bounds__(256)
void k_prep(const float* __restrict__ ctx, const float* __restrict__ Wg,
            const float* __restrict__ Wa,
            float* __restrict__ nrm, float* __restrict__ nsq,
            unsigned short* __restrict__ cnhi, unsigned short* __restrict__ cnlo,
            unsigned short* __restrict__ wgthi, unsigned short* __restrict__ wgtlo,
            unsigned short* __restrict__ wathi, unsigned short* __restrict__ watlo,
            unsigned* __restrict__ cnt)
{
  if (blockIdx.x >= 4096) {
    int wb = blockIdx.x - 4096;
    int j = wb & 255, selA = wb >> 8;
    int k = threadIdx.x;
    if (wb == 0 && k == 0) *cnt = 0u;
    const float* W = selA ? Wa : Wg;
    unsigned short h, l;
    bsplit(W[k * ND + j], h, l);
    if (selA) { wathi[j * ND + k] = h; watlo[j * ND + k] = l; }
    else      { wgthi[j * ND + k] = h; wgtlo[j * ND + k] = l; }
    return;
  }
  int w = threadIdx.x >> 6, lane = threadIdx.x & 63;
  int g = blockIdx.x * 4 + w;
  float4 v = ((const float4*)ctx)[(size_t)g * 64 + lane];
  float ss = v.x*v.x + v.y*v.y + v.z*v.z + v.w*v.w;
  ss = wave_sum(ss);
  float n = sqrtf(ss);
  float rn = 1.f / fmaxf(n, 1e-12f);
  if (lane == 0) { nrm[g] = n; nsq[g] = ss; }
  ushort4 hi, lo;
  bsplit(v.x * rn, hi.x, lo.x);
  bsplit(v.y * rn, hi.y, lo.y);
  bsplit(v.z * rn, hi.z, lo.z);
  bsplit(v.w * rn, hi.w, lo.w);
  ((ushort4*)cnhi)[(size_t)g * 64 + lane] = hi;
  ((ushort4*)cnlo)[(size_t)g * 64 + lane] = lo;
}

// K2: gram via split-bf16 MFMA. 64x64 tile per block over the 8x8 symmetric
// tile grid (36 pairs x 32 batches = 1152 blocks). Each wave computes one
// 32x32 quadrant. Batched, fenced register pipeline (see KLOOP_PIPE).
__global__ __launch_bounds__(256, 2)
void k_gram2(const unsigned short* __restrict__ cnhi, const unsigned short* __restrict__ cnlo,
             const float* __restrict__ nrm,
             float* __restrict__ rowp, float* __restrict__ diag,
             float* __restrict__ pA2, float* __restrict__ pA3,
             unsigned* __restrict__ cnt, unsigned* __restrict__ keys,
             float* __restrict__ vals)
{
  __shared__ float s_row[2][64];
  __shared__ float s_col[2][64];
  __shared__ float sred[8];
  const int bx0 = blockIdx.x;
  const int bx = (bx0 & 7) * 144 + (bx0 >> 3);   // XCD swizzle (1152 = 8*144)
  const int b = bx / 36;
  int rem = bx % 36, ti = 0;
  #pragma unroll
  for (int q = 0; q < 7; ++q) { if (rem >= 8 - ti) { rem -= 8 - ti; ++ti; } }
  const int tj = ti + rem;
  const bool diagT = (ti == tj);
  const int i0 = ti * 64, j0 = tj * 64;
  const int bB = b * NS;
  const int rbA = bB + i0, rbB = bB + j0;

  const int tid = threadIdx.x;
  const int lane = tid & 63, wid = tid >> 6;
  const int l31 = lane & 31, hl = lane >> 5;
  const int wr = wid >> 1, wc = wid & 1;

  const size_t offA = (size_t)(rbA + wr * 32 + l31) * ND + hl * 8;
  const size_t offB = (size_t)(rbB + wc * 32 + l31) * ND + hl * 8;
  const unsigned short* pAh = cnhi + offA;
  const unsigned short* pAl = cnlo + offA;
  const unsigned short* pBh = cnhi + offB;
  const unsigned short* pBl = cnlo + offB;

  f32x16 acc = {};
  short8 s0[4][4], s1[4][4];
  KLOOP_PIPE;

  // ---- epilogue ----
  const float nc = nrm[rbB + wc * 32 + l31];
  const int gcol = wc * 32 + l31;                 // local col 0..63
  float a2 = 0.f, a3 = 0.f, colsum = 0.f;

  #pragma unroll
  for (int r = 0; r < 16; ++r) {
    const int rofs = (r & 3) + 8 * (r >> 2) + 4 * hl;
    const int grow = wr * 32 + rofs;              // local row 0..63
    const float nr = nrm[rbA + grow];
    float v = acc[r];
    float adj = (v > 0.3f) ? v : 0.f;
    float q2 = adj * adj;
    a3 += q2;
    a2 += q2 * nr * nc;
    colsum += adj;
    if (diagT) {
      if (grow == gcol) {
        diag[bB + i0 + grow] = adj;
      } else if (adj > 0.f) {
        unsigned idx = atomicAdd(cnt, 1u);
        if (idx < LIST_CAP) {
          keys[idx] = (unsigned)((bB + i0 + grow) * NS + (j0 + gcol));
          vals[idx] = adj;
        }
      }
    } else if (adj > 0.f) {
      unsigned idx = atomicAdd(cnt, 2u);
      if (idx < LIST_CAP) {
        keys[idx] = (unsigned)((bB + i0 + grow) * NS + (j0 + gcol));
        vals[idx] = adj;
      }
      if (idx + 1u < LIST_CAP) {
        keys[idx + 1u] = (unsigned)((bB + j0 + gcol) * NS + (i0 + grow));
        vals[idx + 1u] = adj;
      }
    }
    float rs = adj;
    rs += __shfl_xor(rs, 1); rs += __shfl_xor(rs, 2); rs += __shfl_xor(rs, 4);
    rs += __shfl_xor(rs, 8); rs += __shfl_xor(rs, 16);
    if (l31 == 0) s_row[wc][grow] = rs;
  }
  colsum += __shfl_xor(colsum, 32);               // add the two hl halves
  if (!diagT && hl == 0) s_col[wr][gcol] = colsum;
  a2 = wave_sum(a2);
  a3 = wave_sum(a3);
  if (lane == 0) { sred[wid] = a2; sred[4 + wid] = a3; }
  __syncthreads();
  if (tid < 64) {
    rowp[tj * 16384 + rbA + tid] = s_row[0][tid] + s_row[1][tid];
    if (!diagT)
      rowp[ti * 16384 + rbB + tid] = s_col[0][tid] + s_col[1][tid];
  }
  if (tid == 0) {
    float f = diagT ? 1.f : 2.f;
    pA2[bx] = f * (sred[0] + sred[1] + sred[2] + sred[3]);
    pA3[bx] = f * (sred[4] + sred[5] + sred[6] + sred[7]);
  }
}

// K3: fused row combine (8 partial slices) + M build + sparse fixup + A1.
__global__ __launch_bounds__(256)
void k_mrow(const float* __restrict__ ctx, const float* __restrict__ rowp,
            const float* __restrict__ nsq, const float* __restrict__ diag,
            const unsigned* __restrict__ cnt, const unsigned* __restrict__ keys,
            const float* __restrict__ vals,
            unsigned short* __restrict__ Mhi, unsigned short* __restrict__ Mlo,
            float* __restrict__ pA1)
{
  __shared__ float sa[4];
  int tid = threadIdx.x, w = tid >> 6, lane = tid & 63;
  int g = blockIdx.x * 4 + w;
  float r = 0.f;
  #pragma unroll
  for (int s = 0; s < 8; ++s) r += rowp[s * 16384 + g];
  float rr = 1.f / (r + 1e-12f);
  float4 v = ((const float4*)ctx)[(size_t)g * 64 + lane];
  float s = diag[g] * rr;
  float mx = v.x * s, my = v.y * s, mz = v.z * s, mw = v.w * s;
  unsigned c = *cnt; if (c > LIST_CAP) c = LIST_CAP;
  for (unsigned e = 0; e < c; ++e) {
    unsigned key = keys[e];
    if ((key >> 9) == (unsigned)g) {
      float vv = vals[e] * rr;
      unsigned bm = ((unsigned)g & ~511u) | (key & 511u);
      float4 cv = ((const float4*)ctx)[(size_t)bm * 64 + lane];
      mx = fmaf(vv, cv.x, mx); my = fmaf(vv, cv.y, my);
      mz = fmaf(vv, cv.z, mz); mw = fmaf(vv, cv.w, mw);
    }
  }
  ushort4 hi, lo;
  bsplit(mx, hi.x, lo.x); bsplit(my, hi.y, lo.y);
  bsplit(mz, hi.z, lo.z); bsplit(mw, hi.w, lo.w);
  ((ushort4*)Mhi)[(size_t)g * 64 + lane] = hi;
  ((ushort4*)Mlo)[(size_t)g * 64 + lane] = lo;
  if (lane == 0) sa[w] = r * nsq[g];
  __syncthreads();
  if (tid == 0) pA1[blockIdx.x] = sa[0] + sa[1] + sa[2] + sa[3];
}

// K4: C = act(A @ W + bias), 64x64 tile per block (grid 256x4 = 1024 blocks),
// one 32x32 quadrant per wave, batched fenced pipeline.
// MODE 0: relu, write bf16 hi/lo only. MODE 1: write fp32 only.
template<int MODE>
__global__ __launch_bounds__(256, 2)
void k_mm(const unsigned short* __restrict__ Ahi, const unsigned short* __restrict__ Alo,
          const unsigned short* __restrict__ Bthi, const unsigned short* __restrict__ Btlo,
          const float* __restrict__ bias, float* __restrict__ outf,
          unsigned short* __restrict__ Ohi, unsigned short* __restrict__ Olo)
{
  const int i0 = blockIdx.x * 64;
  const int c0 = blockIdx.y * 64;
  const int tid = threadIdx.x;
  const int lane = tid & 63, wid = tid >> 6;
  const int l31 = lane & 31, hl = lane >> 5;
  const int wr = wid >> 1, wc = wid & 1;

  const size_t offA = (size_t)(i0 + wr * 32 + l31) * ND + hl * 8;
  const size_t offB = (size_t)(c0 + wc * 32 + l31) * ND + hl * 8;
  const unsigned short* pAh = Ahi + offA;
  const unsigned short* pAl = Alo + offA;
  const unsigned short* pBh = Bthi + offB;
  const unsigned short* pBl = Btlo + offB;

  f32x16 acc = {};
  short8 s0[4][4], s1[4][4];
  KLOOP_PIPE;

  const int gcol = c0 + wc * 32 + l31;
  const float bv = bias[gcol];
  #pragma unroll
  for (int r = 0; r < 16; ++r) {
    const int rofs = (r & 3) + 8 * (r >> 2) + 4 * hl;
    const size_t grow = (size_t)(i0 + wr * 32 + rofs);
    float v = acc[r] + bv;
    if (MODE == 0) {
      v = fmaxf(v, 0.f);
      unsigned short h, l;
      bsplit(v, h, l);
      Ohi[grow * ND + gcol] = h;
      Olo[grow * ND + gcol] = l;
    } else {
      outf[grow * ND + gcol] = v;
    }
  }
}

// K5: per-row LayerNorm -> exact GELU -> dot with W_att2 -> wl
__global__ __launch_bounds__(256)
void k_ln(const float* __restrict__ a, const float* __restrict__ g,
          const float* __restrict__ bt, const float* __restrict__ W2,
          const float* __restrict__ b2, float* __restrict__ wl)
{
  int w = threadIdx.x >> 6, lane = threadIdx.x & 63;
  int row = blockIdx.x * 4 + w;
  float4 x = ((const float4*)a)[(size_t)row * 64 + lane];
  float s = x.x + x.y + x.z + x.w;
  float ss = fmaf(x.x, x.x, fmaf(x.y, x.y, fmaf(x.z, x.z, x.w * x.w)));
  s = wave_sum(s); ss = wave_sum(ss);
  float mu = s * (1.f / 256.f);
  float var = ss * (1.f / 256.f) - mu * mu;
  float rstd = rsqrtf(fmaxf(var, 0.f) + 1e-5f);
  float4 gg = ((const float4*)g)[lane];
  float4 bb = ((const float4*)bt)[lane];
  float4 wv = ((const float4*)W2)[lane];
  const float inv_sqrt2 = 0.70710678118654752f;
  float d = 0.f;
  float y = (x.x - mu) * rstd * gg.x + bb.x;
  d = fmaf(0.5f * y * (1.f + erff(y * inv_sqrt2)), wv.x, d);
  y = (x.y - mu) * rstd * gg.y + bb.y;
  d = fmaf(0.5f * y * (1.f + erff(y * inv_sqrt2)), wv.y, d);
  y = (x.z - mu) * rstd * gg.z + bb.z;
  d = fmaf(0.5f * y * (1.f + erff(y * inv_sqrt2)), wv.z, d);
  y = (x.w - mu) * rstd * gg.w + bb.w;
  d = fmaf(0.5f * y * (1.f + erff(y * inv_sqrt2)), wv.w, d);
  d = wave_sum(d);
  if (lane == 0) wl[row] = d + b2[0];
}

// K6: per-(batch, 32-row chunk) masked softmax (recomputed per block) +
// partial weighted pool of h (reconstructed from bf16 hi/lo). 512 blocks.
__global__ __launch_bounds__(256)
void k_pool2(const float* __restrict__ wl, const int* __restrict__ amask,
             const unsigned short* __restrict__ hhi, const unsigned short* __restrict__ hlo,
             float* __restrict__ part)
{
  __shared__ float sw[512];
  __shared__ float red[256];
  int b = blockIdx.x >> 4, p = blockIdx.x & 15, t = threadIdx.x;
  float l0 = (amask[b * NS + t]       == 0) ? -INFINITY : wl[b * NS + t];
  float l1 = (amask[b * NS + 256 + t] == 0) ? -INFINITY : wl[b * NS + 256 + t];
  red[t] = fmaxf(l0, l1);
  __syncthreads();
  for (int s = 128; s; s >>= 1) { if (t < s) red[t] = fmaxf(red[t], red[t + s]); __syncthreads(); }
  float mx = red[0];
  __syncthreads();
  float e0 = expf(l0 - mx), e1 = expf(l1 - mx);
  red[t] = e0 + e1;
  __syncthreads();
  for (int s = 128; s; s >>= 1) { if (t < s) red[t] += red[t + s]; __syncthreads(); }
  float inv = 1.f / red[0];
  sw[t] = e0 * inv; sw[256 + t] = e1 * inv;
  __syncthreads();
  const size_t base = (size_t)b * NS * ND + (size_t)p * 32 * ND + t;
  float acc = 0.f;
  #pragma unroll 8
  for (int n = 0; n < 32; ++n) {
    float hv = bf16_tof(hhi[base + (size_t)n * ND]) + bf16_tof(hlo[base + (size_t)n * ND]);
    acc = fmaf(sw[p * 32 + n], hv, acc);
  }
  part[(size_t)blockIdx.x * ND + t] = acc;
}

// K7: blocks 0..31: combine pooled partials + logits. Block 32: graph loss.
__global__ __launch_bounds__(256)
void k_final(const float* __restrict__ part, const float* __restrict__ W_out,
             const float* __restrict__ b_out, const float* __restrict__ pA1,
             const float* __restrict__ pA2, const float* __restrict__ pA3,
             float* __restrict__ out)
{
  __shared__ float red[512];
  int t = threadIdx.x;
  if (blockIdx.x < 32) {
    int b = blockIdx.x;
    float pl = 0.f;
    #pragma unroll
    for (int p = 0; p < 16; ++p) pl += part[(size_t)(b * 16 + p) * ND + t];
    red[t]       = pl * W_out[t * 2 + 0];
    red[256 + t] = pl * W_out[t * 2 + 1];
    __syncthreads();
    for (int s = 128; s; s >>= 1) {
      if (t < s) { red[t] += red[t + s]; red[256 + t] += red[256 + t + s]; }
      __syncthreads();
    }
    if (t == 0) {
      out[b * 2 + 0] = red[0]   + b_out[0];
      out[b * 2 + 1] = red[256] + b_out[1];
    }
  } else {
    float r1 = 0.f;
    #pragma unroll
    for (int i = 0; i < 16; ++i) r1 += pA1[i * 256 + t];
    float r2 = 0.f, r3 = 0.f;
    #pragma unroll
    for (int i = 0; i < 5; ++i) {
      int idx = i * 256 + t;
      if (idx < 1152) { r2 += pA2[idx]; r3 += pA3[idx]; }
    }
    red[t] = r1; red[256 + t] = r2;
    __syncthreads();
    for (int s = 128; s; s >>= 1) {
      if (t < s) { red[t] += red[t + s]; red[256 + t] += red[256 + t + s]; }
      __syncthreads();
    }
    r1 = red[0]; r2 = red[256];
    __syncthreads();
    red[t] = r3;
    __syncthreads();
    for (int s = 128; s; s >>= 1) { if (t < s) red[t] += red[t + s]; __syncthreads(); }
    if (t == 0) {
      float smooth = 0.2f * (r1 - r2) * (1.f / (32.f * 512.f * 512.f));
      float spars  = 0.1f * red[0] * (1.f / (512.f * 512.f)) * (1.f / 32.f);
      out[64] = smooth + spars;
    }
  }
}

extern "C" void kernel_launch(void* const* d_in, const int* in_sizes, int n_in,
                              void* d_out, int out_size, void* d_ws, size_t ws_size,
                              hipStream_t stream)
{
  (void)in_sizes; (void)n_in; (void)out_size; (void)ws_size;
  const float* ctx    = (const float*)d_in[0];
  const int*   amask  = (const int*)d_in[1];
  const float* W_gcn  = (const float*)d_in[2];
  const float* b_gcn  = (const float*)d_in[3];
  const float* W_att1 = (const float*)d_in[4];
  const float* b_att1 = (const float*)d_in[5];
  const float* ln_g   = (const float*)d_in[6];
  const float* ln_b   = (const float*)d_in[7];
  const float* W_att2 = (const float*)d_in[8];
  const float* b_att2 = (const float*)d_in[9];
  const float* W_out  = (const float*)d_in[10];
  const float* b_out  = (const float*)d_in[11];
  float* out = (float*)d_out;

  float* ws = (float*)d_ws;
  // W0 (16.8 MB): cn hi/lo, later reused as h hi/lo
  unsigned short* cnhi = (unsigned short*)ws;
  unsigned short* cnlo = (unsigned short*)(ws + 2097152);
  unsigned short* hhi  = cnhi;
  unsigned short* hlo  = cnlo;
  // W1 (16.8 MB): part (512*256 floats) + spare
  float* part = ws + 4194304;
  // W2 (16.8 MB): M hi/lo, later reused as 'a' fp32
  unsigned short* Mhi = (unsigned short*)(ws + 8388608);
  unsigned short* Mlo = (unsigned short*)(ws + 8388608 + 2097152);
  float* abuf = ws + 8388608;
  // small region
  float* sp   = ws + 12582912;
  float* nrm  = sp;            sp += 16384;
  float* nsq  = sp;            sp += 16384;
  float* rowp = sp;            sp += 131072;   // 8 partial slices
  float* diag = sp;            sp += 16384;
  float* wl   = sp;            sp += 16384;
  float* pA1  = sp;            sp += 4096;
  float* pA2  = sp;            sp += 1280;
  float* pA3  = sp;            sp += 1280;
  unsigned* cnt  = (unsigned*)sp;  sp += 64;
  unsigned* keys = (unsigned*)sp;  sp += 32768;
  float* vals = sp;            sp += 32768;
  unsigned short* wgthi = (unsigned short*)sp; sp += 32768;
  unsigned short* wgtlo = (unsigned short*)sp; sp += 32768;
  unsigned short* wathi = (unsigned short*)sp; sp += 32768;
  unsigned short* watlo = (unsigned short*)sp; sp += 32768;

  k_prep<<<4608, 256, 0, stream>>>(ctx, W_gcn, W_att1, nrm, nsq, cnhi, cnlo,
                                   wgthi, wgtlo, wathi, watlo, cnt);
  k_gram2<<<1152, 256, 0, stream>>>(cnhi, cnlo, nrm, rowp, diag, pA2, pA3,
                                    cnt, keys, vals);
  k_mrow<<<4096, 256, 0, stream>>>(ctx, rowp, nsq, diag, cnt, keys, vals,
                                   Mhi, Mlo, pA1);
  k_mm<0><<<dim3(256, 4), 256, 0, stream>>>(Mhi, Mlo, wgthi, wgtlo, b_gcn,
                                            nullptr, hhi, hlo);
  k_mm<1><<<dim3(256, 4), 256, 0, stream>>>(hhi, hlo, wathi, watlo, b_att1,
                                            abuf, nullptr, nullptr);
  k_ln<<<4096, 256, 0, stream>>>(abuf, ln_g, ln_b, W_att2, b_att2, wl);
  k_pool2<<<512, 256, 0, stream>>>(wl, amask, hhi, hlo, part);
  k_final<<<33, 256, 0, stream>>>(part, W_out, b_out, pA1, pA2, pA3, out);
}

// Round 6
// 84.884 us; speedup vs baseline: 1.7020x; 1.6934x over previous
//
#include <hip/hip_runtime.h>
#include <math.h>

#define NS 512
#define ND 256
#define LIST_CAP 32768u

typedef short short8 __attribute__((ext_vector_type(8)));
typedef float f32x16 __attribute__((ext_vector_type(16)));

__device__ __forceinline__ unsigned short bf16_rne(float x) {
  unsigned u = __float_as_uint(x);
  unsigned r = u + 0x7fffu + ((u >> 16) & 1u);
  return (unsigned short)(r >> 16);
}
__device__ __forceinline__ float bf16_tof(unsigned short h) {
  return __uint_as_float(((unsigned)h) << 16);
}
__device__ __forceinline__ void bsplit(float x, unsigned short& h, unsigned short& l) {
  h = bf16_rne(x);
  l = bf16_rne(x - bf16_tof(h));
}
__device__ __forceinline__ float wave_sum(float v) {
  v += __shfl_xor(v, 1);  v += __shfl_xor(v, 2);  v += __shfl_xor(v, 4);
  v += __shfl_xor(v, 8);  v += __shfl_xor(v, 16); v += __shfl_xor(v, 32);
  return v;
}

// ---- LDS staging (coalesced, swizzled) -------------------------------------
// LDS arena: 4 pieces of 8 KB: [Ahi][Alo][Bhi][Blo], each 64 rows x 64 k bf16,
// row stride 128 B, XOR-swizzled within the row: content byte for (row, off)
// lives at row*128 + (off ^ ((row&7)<<4)). gload_lds dest stays linear; the
// swizzle is applied on the per-lane GLOBAL source address (rule 21 / m173).

__device__ __forceinline__ void gload_lds16(const void* g, void* l) {
  __builtin_amdgcn_global_load_lds(
      (const __attribute__((address_space(1))) unsigned int*)g,
      (__attribute__((address_space(3))) unsigned int*)l, 16, 0, 0);
}

// stage one 64x64 tile-pair set (A hi/lo rows grA.., B hi/lo rows grB..) at
// k offset k0 into the 32KB arena. 8 gload_lds per thread.
__device__ __forceinline__ void stage4(const unsigned short* __restrict__ hiA,
                                       const unsigned short* __restrict__ loA, int grA,
                                       const unsigned short* __restrict__ hiB,
                                       const unsigned short* __restrict__ loB, int grB,
                                       int k0, char* lds, int wid, int lane)
{
  #pragma unroll
  for (int q = 0; q < 2; ++q) {
    const int c = (q * 4 + wid) * 64 + lane;          // chunk 0..511
    const int row = c >> 3;
    const int soff = ((c & 7) * 16) ^ ((row & 7) << 4);  // swizzled byte off in row
    const int dest = (q * 4 + wid) * 1024;            // wave-uniform dest base
    const size_t ga = (size_t)(grA + row) * ND + k0 + (soff >> 1);
    const size_t gb = (size_t)(grB + row) * ND + k0 + (soff >> 1);
    gload_lds16(hiA + ga, lds + dest);
    gload_lds16(loA + ga, lds + 8192 + dest);
    gload_lds16(hiB + gb, lds + 16384 + dest);
    gload_lds16(loB + gb, lds + 24576 + dest);
  }
}

// swizzled read address for (row, byte-off within 128B row)
#define SWZB(row, off) (((row) << 7) + (((off) ^ (((row) & 7) << 4))))

// 12 MFMAs for one BK=64 step: split-bf16 hi*hi + hi*lo + lo*hi.
#define STEP_MFMA(lds, arow, brow) do { \
  _Pragma("unroll") \
  for (int ks = 0; ks < 4; ++ks) { \
    const int off = ks * 32 + hl * 16; \
    short8 ah = *(const short8*)((lds) + SWZB((arow), off)); \
    short8 al = *(const short8*)((lds) + 8192 + SWZB((arow), off)); \
    short8 bh = *(const short8*)((lds) + 16384 + SWZB((brow), off)); \
    short8 bl = *(const short8*)((lds) + 24576 + SWZB((brow), off)); \
    acc = __builtin_amdgcn_mfma_f32_32x32x16_bf16(ah, bh, acc, 0, 0, 0); \
    acc = __builtin_amdgcn_mfma_f32_32x32x16_bf16(ah, bl, acc, 0, 0, 0); \
    acc = __builtin_amdgcn_mfma_f32_32x32x16_bf16(al, bh, acc, 0, 0, 0); \
  } \
} while (0)

// K1: norms + normalized bf16 split of context; fused weight transpose+split;
// zero sparse counter. Blocks 0..4095: ctx rows; 4096..4607: W cols.
__global__ __launch_bounds__(256)
void k_prep(const float* __restrict__ ctx, const float* __restrict__ Wg,
            const float* __restrict__ Wa,
            float* __restrict__ nrm, float* __restrict__ nsq,
            unsigned short* __restrict__ cnhi, unsigned short* __restrict__ cnlo,
            unsigned short* __restrict__ wgthi, unsigned short* __restrict__ wgtlo,
            unsigned short* __restrict__ wathi, unsigned short* __restrict__ watlo,
            unsigned* __restrict__ cnt)
{
  if (blockIdx.x >= 4096) {
    int wb = blockIdx.x - 4096;
    int j = wb & 255, selA = wb >> 8;
    int k = threadIdx.x;
    if (wb == 0 && k == 0) *cnt = 0u;
    const float* W = selA ? Wa : Wg;
    unsigned short h, l;
    bsplit(W[k * ND + j], h, l);
    if (selA) { wathi[j * ND + k] = h; watlo[j * ND + k] = l; }
    else      { wgthi[j * ND + k] = h; wgtlo[j * ND + k] = l; }
    return;
  }
  int w = threadIdx.x >> 6, lane = threadIdx.x & 63;
  int g = blockIdx.x * 4 + w;
  float4 v = ((const float4*)ctx)[(size_t)g * 64 + lane];
  float ss = v.x*v.x + v.y*v.y + v.z*v.z + v.w*v.w;
  ss = wave_sum(ss);
  float n = sqrtf(ss);
  float rn = 1.f / fmaxf(n, 1e-12f);
  if (lane == 0) { nrm[g] = n; nsq[g] = ss; }
  ushort4 hi, lo;
  bsplit(v.x * rn, hi.x, lo.x);
  bsplit(v.y * rn, hi.y, lo.y);
  bsplit(v.z * rn, hi.z, lo.z);
  bsplit(v.w * rn, hi.w, lo.w);
  ((ushort4*)cnhi)[(size_t)g * 64 + lane] = hi;
  ((ushort4*)cnlo)[(size_t)g * 64 + lane] = lo;
}

// K2: gram via split-bf16 MFMA, 64x64 tile per block over the 8x8 symmetric
// tile grid (36 pairs x 32 batches = 1152 blocks), LDS-staged (coalesced
// global_load_lds + swizzled ds_read). Each wave computes one 32x32 quadrant.
__global__ __launch_bounds__(256, 4)
void k_gram2(const unsigned short* __restrict__ cnhi, const unsigned short* __restrict__ cnlo,
             const float* __restrict__ nrm,
             float* __restrict__ rowp, float* __restrict__ diag,
             float* __restrict__ pA2, float* __restrict__ pA3,
             unsigned* __restrict__ cnt, unsigned* __restrict__ keys,
             float* __restrict__ vals)
{
  __shared__ __align__(16) char lds[32768];
  __shared__ float s_row[2][64];
  __shared__ float s_col[2][64];
  __shared__ float sred[8];
  const int bx0 = blockIdx.x;
  const int bx = (bx0 & 7) * 144 + (bx0 >> 3);   // XCD swizzle (1152 = 8*144)
  const int b = bx / 36;
  int rem = bx % 36, ti = 0;
  #pragma unroll
  for (int q = 0; q < 7; ++q) { if (rem >= 8 - ti) { rem -= 8 - ti; ++ti; } }
  const int tj = ti + rem;
  const bool diagT = (ti == tj);
  const int i0 = ti * 64, j0 = tj * 64;
  const int bB = b * NS;
  const int rbA = bB + i0, rbB = bB + j0;

  const int tid = threadIdx.x;
  const int lane = tid & 63, wid = tid >> 6;
  const int l31 = lane & 31, hl = lane >> 5;
  const int wr = wid >> 1, wc = wid & 1;
  const int arow = wr * 32 + l31;
  const int brow = wc * 32 + l31;

  f32x16 acc = {};
  #pragma unroll
  for (int t = 0; t < 4; ++t) {
    stage4(cnhi, cnlo, rbA, cnhi, cnlo, rbB, t * 64, lds, wid, lane);
    __syncthreads();                 // drains vmcnt -> LDS tile ready
    STEP_MFMA(lds, arow, brow);
    __syncthreads();                 // all reads done before next overwrite
  }

  // ---- epilogue (verified, unchanged) ----
  const float nc = nrm[rbB + wc * 32 + l31];
  const int gcol = wc * 32 + l31;                 // local col 0..63
  float a2 = 0.f, a3 = 0.f, colsum = 0.f;

  #pragma unroll
  for (int r = 0; r < 16; ++r) {
    const int rofs = (r & 3) + 8 * (r >> 2) + 4 * hl;
    const int grow = wr * 32 + rofs;              // local row 0..63
    const float nr = nrm[rbA + grow];
    float v = acc[r];
    float adj = (v > 0.3f) ? v : 0.f;
    float q2 = adj * adj;
    a3 += q2;
    a2 += q2 * nr * nc;
    colsum += adj;
    if (diagT) {
      if (grow == gcol) {
        diag[bB + i0 + grow] = adj;
      } else if (adj > 0.f) {
        unsigned idx = atomicAdd(cnt, 1u);
        if (idx < LIST_CAP) {
          keys[idx] = (unsigned)((bB + i0 + grow) * NS + (j0 + gcol));
          vals[idx] = adj;
        }
      }
    } else if (adj > 0.f) {
      unsigned idx = atomicAdd(cnt, 2u);
      if (idx < LIST_CAP) {
        keys[idx] = (unsigned)((bB + i0 + grow) * NS + (j0 + gcol));
        vals[idx] = adj;
      }
      if (idx + 1u < LIST_CAP) {
        keys[idx + 1u] = (unsigned)((bB + j0 + gcol) * NS + (i0 + grow));
        vals[idx + 1u] = adj;
      }
    }
    float rs = adj;
    rs += __shfl_xor(rs, 1); rs += __shfl_xor(rs, 2); rs += __shfl_xor(rs, 4);
    rs += __shfl_xor(rs, 8); rs += __shfl_xor(rs, 16);
    if (l31 == 0) s_row[wc][grow] = rs;
  }
  colsum += __shfl_xor(colsum, 32);               // add the two hl halves
  if (!diagT && hl == 0) s_col[wr][gcol] = colsum;
  a2 = wave_sum(a2);
  a3 = wave_sum(a3);
  if (lane == 0) { sred[wid] = a2; sred[4 + wid] = a3; }
  __syncthreads();
  if (tid < 64) {
    rowp[tj * 16384 + rbA + tid] = s_row[0][tid] + s_row[1][tid];
    if (!diagT)
      rowp[ti * 16384 + rbB + tid] = s_col[0][tid] + s_col[1][tid];
  }
  if (tid == 0) {
    float f = diagT ? 1.f : 2.f;
    pA2[bx] = f * (sred[0] + sred[1] + sred[2] + sred[3]);
    pA3[bx] = f * (sred[4] + sred[5] + sred[6] + sred[7]);
  }
}

// K3: fused row combine (8 partial slices) + M build + sparse fixup + A1.
__global__ __launch_bounds__(256)
void k_mrow(const float* __restrict__ ctx, const float* __restrict__ rowp,
            const float* __restrict__ nsq, const float* __restrict__ diag,
            const unsigned* __restrict__ cnt, const unsigned* __restrict__ keys,
            const float* __restrict__ vals,
            unsigned short* __restrict__ Mhi, unsigned short* __restrict__ Mlo,
            float* __restrict__ pA1)
{
  __shared__ float sa[4];
  int tid = threadIdx.x, w = tid >> 6, lane = tid & 63;
  int g = blockIdx.x * 4 + w;
  float r = 0.f;
  #pragma unroll
  for (int s = 0; s < 8; ++s) r += rowp[s * 16384 + g];
  float rr = 1.f / (r + 1e-12f);
  float4 v = ((const float4*)ctx)[(size_t)g * 64 + lane];
  float s = diag[g] * rr;
  float mx = v.x * s, my = v.y * s, mz = v.z * s, mw = v.w * s;
  unsigned c = *cnt; if (c > LIST_CAP) c = LIST_CAP;
  for (unsigned e = 0; e < c; ++e) {
    unsigned key = keys[e];
    if ((key >> 9) == (unsigned)g) {
      float vv = vals[e] * rr;
      unsigned bm = ((unsigned)g & ~511u) | (key & 511u);
      float4 cv = ((const float4*)ctx)[(size_t)bm * 64 + lane];
      mx = fmaf(vv, cv.x, mx); my = fmaf(vv, cv.y, my);
      mz = fmaf(vv, cv.z, mz); mw = fmaf(vv, cv.w, mw);
    }
  }
  ushort4 hi, lo;
  bsplit(mx, hi.x, lo.x); bsplit(my, hi.y, lo.y);
  bsplit(mz, hi.z, lo.z); bsplit(mw, hi.w, lo.w);
  ((ushort4*)Mhi)[(size_t)g * 64 + lane] = hi;
  ((ushort4*)Mlo)[(size_t)g * 64 + lane] = lo;
  if (lane == 0) sa[w] = r * nsq[g];
  __syncthreads();
  if (tid == 0) pA1[blockIdx.x] = sa[0] + sa[1] + sa[2] + sa[3];
}

// K4: C = act(A @ W + bias), 64x64 tile per block (grid 256x4 = 1024 blocks),
// LDS-staged like k_gram2; one 32x32 quadrant per wave.
// MODE 0: relu, write bf16 hi/lo only. MODE 1: write fp32 only.
template<int MODE>
__global__ __launch_bounds__(256, 4)
void k_mm(const unsigned short* __restrict__ Ahi, const unsigned short* __restrict__ Alo,
          const unsigned short* __restrict__ Bthi, const unsigned short* __restrict__ Btlo,
          const float* __restrict__ bias, float* __restrict__ outf,
          unsigned short* __restrict__ Ohi, unsigned short* __restrict__ Olo)
{
  __shared__ __align__(16) char lds[32768];
  const int i0 = blockIdx.x * 64;
  const int c0 = blockIdx.y * 64;
  const int tid = threadIdx.x;
  const int lane = tid & 63, wid = tid >> 6;
  const int l31 = lane & 31, hl = lane >> 5;
  const int wr = wid >> 1, wc = wid & 1;
  const int arow = wr * 32 + l31;
  const int brow = wc * 32 + l31;

  f32x16 acc = {};
  #pragma unroll
  for (int t = 0; t < 4; ++t) {
    stage4(Ahi, Alo, i0, Bthi, Btlo, c0, t * 64, lds, wid, lane);
    __syncthreads();
    STEP_MFMA(lds, arow, brow);
    __syncthreads();
  }

  const int gcol = c0 + wc * 32 + l31;
  const float bv = bias[gcol];
  #pragma unroll
  for (int r = 0; r < 16; ++r) {
    const int rofs = (r & 3) + 8 * (r >> 2) + 4 * hl;
    const size_t grow = (size_t)(i0 + wr * 32 + rofs);
    float v = acc[r] + bv;
    if (MODE == 0) {
      v = fmaxf(v, 0.f);
      unsigned short h, l;
      bsplit(v, h, l);
      Ohi[grow * ND + gcol] = h;
      Olo[grow * ND + gcol] = l;
    } else {
      outf[grow * ND + gcol] = v;
    }
  }
}

// K5: per-row LayerNorm -> exact GELU -> dot with W_att2 -> wl
__global__ __launch_bounds__(256)
void k_ln(const float* __restrict__ a, const float* __restrict__ g,
          const float* __restrict__ bt, const float* __restrict__ W2,
          const float* __restrict__ b2, float* __restrict__ wl)
{
  int w = threadIdx.x >> 6, lane = threadIdx.x & 63;
  int row = blockIdx.x * 4 + w;
  float4 x = ((const float4*)a)[(size_t)row * 64 + lane];
  float s = x.x + x.y + x.z + x.w;
  float ss = fmaf(x.x, x.x, fmaf(x.y, x.y, fmaf(x.z, x.z, x.w * x.w)));
  s = wave_sum(s); ss = wave_sum(ss);
  float mu = s * (1.f / 256.f);
  float var = ss * (1.f / 256.f) - mu * mu;
  float rstd = rsqrtf(fmaxf(var, 0.f) + 1e-5f);
  float4 gg = ((const float4*)g)[lane];
  float4 bb = ((const float4*)bt)[lane];
  float4 wv = ((const float4*)W2)[lane];
  const float inv_sqrt2 = 0.70710678118654752f;
  float d = 0.f;
  float y = (x.x - mu) * rstd * gg.x + bb.x;
  d = fmaf(0.5f * y * (1.f + erff(y * inv_sqrt2)), wv.x, d);
  y = (x.y - mu) * rstd * gg.y + bb.y;
  d = fmaf(0.5f * y * (1.f + erff(y * inv_sqrt2)), wv.y, d);
  y = (x.z - mu) * rstd * gg.z + bb.z;
  d = fmaf(0.5f * y * (1.f + erff(y * inv_sqrt2)), wv.z, d);
  y = (x.w - mu) * rstd * gg.w + bb.w;
  d = fmaf(0.5f * y * (1.f + erff(y * inv_sqrt2)), wv.w, d);
  d = wave_sum(d);
  if (lane == 0) wl[row] = d + b2[0];
}

// K6: per-(batch, 32-row chunk) masked softmax (recomputed per block) +
// partial weighted pool of h (reconstructed from bf16 hi/lo). 512 blocks.
__global__ __launch_bounds__(256)
void k_pool2(const float* __restrict__ wl, const int* __restrict__ amask,
             const unsigned short* __restrict__ hhi, const unsigned short* __restrict__ hlo,
             float* __restrict__ part)
{
  __shared__ float sw[512];
  __shared__ float red[256];
  int b = blockIdx.x >> 4, p = blockIdx.x & 15, t = threadIdx.x;
  float l0 = (amask[b * NS + t]       == 0) ? -INFINITY : wl[b * NS + t];
  float l1 = (amask[b * NS + 256 + t] == 0) ? -INFINITY : wl[b * NS + 256 + t];
  red[t] = fmaxf(l0, l1);
  __syncthreads();
  for (int s = 128; s; s >>= 1) { if (t < s) red[t] = fmaxf(red[t], red[t + s]); __syncthreads(); }
  float mx = red[0];
  __syncthreads();
  float e0 = expf(l0 - mx), e1 = expf(l1 - mx);
  red[t] = e0 + e1;
  __syncthreads();
  for (int s = 128; s; s >>= 1) { if (t < s) red[t] += red[t + s]; __syncthreads(); }
  float inv = 1.f / red[0];
  sw[t] = e0 * inv; sw[256 + t] = e1 * inv;
  __syncthreads();
  const size_t base = (size_t)b * NS * ND + (size_t)p * 32 * ND + t;
  float acc = 0.f;
  #pragma unroll 8
  for (int n = 0; n < 32; ++n) {
    float hv = bf16_tof(hhi[base + (size_t)n * ND]) + bf16_tof(hlo[base + (size_t)n * ND]);
    acc = fmaf(sw[p * 32 + n], hv, acc);
  }
  part[(size_t)blockIdx.x * ND + t] = acc;
}

// K7: blocks 0..31: combine pooled partials + logits. Block 32: graph loss.
__global__ __launch_bounds__(256)
void k_final(const float* __restrict__ part, const float* __restrict__ W_out,
             const float* __restrict__ b_out, const float* __restrict__ pA1,
             const float* __restrict__ pA2, const float* __restrict__ pA3,
             float* __restrict__ out)
{
  __shared__ float red[512];
  int t = threadIdx.x;
  if (blockIdx.x < 32) {
    int b = blockIdx.x;
    float pl = 0.f;
    #pragma unroll
    for (int p = 0; p < 16; ++p) pl += part[(size_t)(b * 16 + p) * ND + t];
    red[t]       = pl * W_out[t * 2 + 0];
    red[256 + t] = pl * W_out[t * 2 + 1];
    __syncthreads();
    for (int s = 128; s; s >>= 1) {
      if (t < s) { red[t] += red[t + s]; red[256 + t] += red[256 + t + s]; }
      __syncthreads();
    }
    if (t == 0) {
      out[b * 2 + 0] = red[0]   + b_out[0];
      out[b * 2 + 1] = red[256] + b_out[1];
    }
  } else {
    float r1 = 0.f;
    #pragma unroll
    for (int i = 0; i < 16; ++i) r1 += pA1[i * 256 + t];
    float r2 = 0.f, r3 = 0.f;
    #pragma unroll
    for (int i = 0; i < 5; ++i) {
      int idx = i * 256 + t;
      if (idx < 1152) { r2 += pA2[idx]; r3 += pA3[idx]; }
    }
    red[t] = r1; red[256 + t] = r2;
    __syncthreads();
    for (int s = 128; s; s >>= 1) {
      if (t < s) { red[t] += red[t + s]; red[256 + t] += red[256 + t + s]; }
      __syncthreads();
    }
    r1 = red[0]; r2 = red[256];
    __syncthreads();
    red[t] = r3;
    __syncthreads();
    for (int s = 128; s; s >>= 1) { if (t < s) red[t] += red[t + s]; __syncthreads(); }
    if (t == 0) {
      float smooth = 0.2f * (r1 - r2) * (1.f / (32.f * 512.f * 512.f));
      float spars  = 0.1f * red[0] * (1.f / (512.f * 512.f)) * (1.f / 32.f);
      out[64] = smooth + spars;
    }
  }
}

extern "C" void kernel_launch(void* const* d_in, const int* in_sizes, int n_in,
                              void* d_out, int out_size, void* d_ws, size_t ws_size,
                              hipStream_t stream)
{
  (void)in_sizes; (void)n_in; (void)out_size; (void)ws_size;
  const float* ctx    = (const float*)d_in[0];
  const int*   amask  = (const int*)d_in[1];
  const float* W_gcn  = (const float*)d_in[2];
  const float* b_gcn  = (const float*)d_in[3];
  const float* W_att1 = (const float*)d_in[4];
  const float* b_att1 = (const float*)d_in[5];
  const float* ln_g   = (const float*)d_in[6];
  const float* ln_b   = (const float*)d_in[7];
  const float* W_att2 = (const float*)d_in[8];
  const float* b_att2 = (const float*)d_in[9];
  const float* W_out  = (const float*)d_in[10];
  const float* b_out  = (const float*)d_in[11];
  float* out = (float*)d_out;

  float* ws = (float*)d_ws;
  // W0 (16.8 MB): cn hi/lo, later reused as h hi/lo
  unsigned short* cnhi = (unsigned short*)ws;
  unsigned short* cnlo = (unsigned short*)(ws + 2097152);
  unsigned short* hhi  = cnhi;
  unsigned short* hlo  = cnlo;
  // W1 (16.8 MB): part (512*256 floats) + spare
  float* part = ws + 4194304;
  // W2 (16.8 MB): M hi/lo, later reused as 'a' fp32
  unsigned short* Mhi = (unsigned short*)(ws + 8388608);
  unsigned short* Mlo = (unsigned short*)(ws + 8388608 + 2097152);
  float* abuf = ws + 8388608;
  // small region
  float* sp   = ws + 12582912;
  float* nrm  = sp;            sp += 16384;
  float* nsq  = sp;            sp += 16384;
  float* rowp = sp;            sp += 131072;   // 8 partial slices
  float* diag = sp;            sp += 16384;
  float* wl   = sp;            sp += 16384;
  float* pA1  = sp;            sp += 4096;
  float* pA2  = sp;            sp += 1280;
  float* pA3  = sp;            sp += 1280;
  unsigned* cnt  = (unsigned*)sp;  sp += 64;
  unsigned* keys = (unsigned*)sp;  sp += 32768;
  float* vals = sp;            sp += 32768;
  unsigned short* wgthi = (unsigned short*)sp; sp += 32768;
  unsigned short* wgtlo = (unsigned short*)sp; sp += 32768;
  unsigned short* wathi = (unsigned short*)sp; sp += 32768;
  unsigned short* watlo = (unsigned short*)sp; sp += 32768;

  k_prep<<<4608, 256, 0, stream>>>(ctx, W_gcn, W_att1, nrm, nsq, cnhi, cnlo,
                                   wgthi, wgtlo, wathi, watlo, cnt);
  k_gram2<<<1152, 256, 0, stream>>>(cnhi, cnlo, nrm, rowp, diag, pA2, pA3,
                                    cnt, keys, vals);
  k_mrow<<<4096, 256, 0, stream>>>(ctx, rowp, nsq, diag, cnt, keys, vals,
                                   Mhi, Mlo, pA1);
  k_mm<0><<<dim3(256, 4), 256, 0, stream>>>(Mhi, Mlo, wgthi, wgtlo, b_gcn,
                                            nullptr, hhi, hlo);
  k_mm<1><<<dim3(256, 4), 256, 0, stream>>>(hhi, hlo, wathi, watlo, b_att1,
                                            abuf, nullptr, nullptr);
  k_ln<<<4096, 256, 0, stream>>>(abuf, ln_g, ln_b, W_att2, b_att2, wl);
  k_pool2<<<512, 256, 0, stream>>>(wl, amask, hhi, hlo, part);
  k_final<<<33, 256, 0, stream>>>(part, W_out, b_out, pA1, pA2, pA3, out);
}